// Round 4
// baseline (132.981 us; speedup 1.0000x reference)
//
#include <hip/hip_runtime.h>
#include <stdint.h>

#define N 2048
#define F 128
#define ALPHA 1.0f
#define PB 128   // producer blocks (each owns 16 rows of the sigma partials)

typedef __bf16 bf16x8 __attribute__((ext_vector_type(8)));
typedef float f32x4 __attribute__((ext_vector_type(4)));

// ws layout:
//   [0, 64K)   : s_part[128][PB]  - column-sum partials, K-MAJOR: s_part[k][b]
//   then 512 B : nsum_part[PB]    - per-producer-block sum of row norms
//   then 1 KB  : flags[PB] (u64)  - data-derived magic pair {M, ~M}
static constexpr size_t WS_SP   = 0;
static constexpr size_t WS_NS   = (size_t)F * PB * 4;     // 65536
static constexpr size_t WS_FLAG = WS_NS + (size_t)PB * 4; // 66048 (8B aligned)

// Single fused kernel. Grid (32,16) = 512 blocks of 256 threads.
// Only cross-block dependency is the scalar sigma; fragments/norms/MFMA are
// block-local, built from fp32 X directly ((__bf16) cast = RNE, same as the
// validated bit-trick). All 512 blocks co-resident: launch_bounds(256,2)
// guarantees 2 blocks/CU (8 waves/CU, VGPR cap 256) x 256 CUs = 512 slots.
// The flag spin is BOUNDED: on protocol failure we produce wrong sigma and a
// diagnosable correctness failure instead of a hung container.
__global__ __launch_bounds__(256, 2) void gk_fused(
    const float* __restrict__ X,
    float* __restrict__ s_part,
    float* __restrict__ nsum_part,
    unsigned long long* __restrict__ flags,
    float* __restrict__ out)
{
    __shared__ float s_lds[F];
    __shared__ float nw_lds[4];
    __shared__ float red[8];

    const int t = threadIdx.x;
    const int bid = blockIdx.y * 32 + blockIdx.x;
    const int wave = t >> 6, lane = t & 63;
    const int quad = lane >> 4, l16 = lane & 15;

    // Poison-proof flag value: pair (M, ~M) in one 64-bit word, M data-derived.
    // No uniform 4-byte fill pattern p can satisfy lo==M && hi==~M.
    const unsigned int MAGIC = __float_as_uint(X[0]) ^ 0xB5297A4Du;
    const unsigned long long FLAGVAL =
        (unsigned long long)MAGIC | ((unsigned long long)(~MAGIC) << 32);

    // ---------------- producer share: colsum + norm-sum partials -----------
    if (bid < PB) {
        if (t < F) s_lds[t] = 0.f;
        __syncthreads();
        const int r = t >> 4, kidx = t & 15, k0 = kidx * 8;
        const int row = bid * 16 + r;
        const float4* px = reinterpret_cast<const float4*>(X + (size_t)row * F + k0);
        float4 v0 = px[0], v1 = px[1];
        float xv[8] = {v0.x, v0.y, v0.z, v0.w, v1.x, v1.y, v1.z, v1.w};
        float xb[8];
        float ns = 0.f;
#pragma unroll
        for (int j = 0; j < 8; ++j) {
            uint32_t u = __float_as_uint(xv[j]);
            u = (u + 0x7FFFu + ((u >> 16) & 1u)) >> 16;   // RNE to bf16
            float fb = __uint_as_float(u << 16);
            xb[j] = fb;
            ns += fb * fb;
        }
        // wave sum of row-norm partials (wave covers 4 rows x 16 chunks)
        float nsr = ns;
#pragma unroll
        for (int off = 1; off < 64; off <<= 1) nsr += __shfl_xor(nsr, off, 64);
        if (lane == 0) nw_lds[wave] = nsr;
        // column partials: reduce 4 rows within wave, 4-way LDS atomics across waves
#pragma unroll
        for (int j = 0; j < 8; ++j) {
            float cj = xb[j];
            cj += __shfl_xor(cj, 16, 64);
            cj += __shfl_xor(cj, 32, 64);
            if ((t & 48) == 0) atomicAdd(&s_lds[k0 + j], cj);
        }
        __syncthreads();   // waitcnt drain: all lanes' stores reach L2 below
        if (t < F) s_part[(size_t)t * PB + bid] = s_lds[t];
        if (t == 0) nsum_part[bid] = nw_lds[0] + nw_lds[1] + nw_lds[2] + nw_lds[3];
        __threadfence();   // agent fence: L2 writeback so other XCDs can see
        __syncthreads();
        if (t == 0)
            __hip_atomic_store(&flags[bid], FLAGVAL, __ATOMIC_RELEASE,
                               __HIP_MEMORY_SCOPE_AGENT);
    }

    // ---------------- block-local: fragments + norms + MFMA ----------------
    const int row0 = blockIdx.y * 128 + wave * 32;
    const int col0 = blockIdx.x * 64;

    // A/B fragment layout (validated in round 2): for MFMA kc, lane (quad,l16)
    // holds row/col (base+l16), k = kc*32 + quad*8 + j  (j=0..7).
    bf16x8 afr[2][4];
    float nr[2];
#pragma unroll
    for (int mi = 0; mi < 2; ++mi) {
        const float* base = X + (size_t)(row0 + mi * 16 + l16) * F;
        float s = 0.f;
#pragma unroll
        for (int kc = 0; kc < 4; ++kc) {
            const float4* p = reinterpret_cast<const float4*>(base + (kc * 4 + quad) * 8);
            float4 a = p[0], b = p[1];
            bf16x8 f;
            f[0] = (__bf16)a.x; f[1] = (__bf16)a.y; f[2] = (__bf16)a.z; f[3] = (__bf16)a.w;
            f[4] = (__bf16)b.x; f[5] = (__bf16)b.y; f[6] = (__bf16)b.z; f[7] = (__bf16)b.w;
            afr[mi][kc] = f;
#pragma unroll
            for (int j = 0; j < 8; ++j) { float v = (float)f[j]; s += v * v; }
        }
        s += __shfl_xor(s, 16, 64);
        s += __shfl_xor(s, 32, 64);   // full-k norm of row row0+mi*16+l16
        nr[mi] = s;
    }

    bf16x8 bfr[4][4];
    float cn[4];
#pragma unroll
    for (int ni = 0; ni < 4; ++ni) {
        const float* base = X + (size_t)(col0 + ni * 16 + l16) * F;
        float s = 0.f;
#pragma unroll
        for (int kc = 0; kc < 4; ++kc) {
            const float4* p = reinterpret_cast<const float4*>(base + (kc * 4 + quad) * 8);
            float4 a = p[0], b = p[1];
            bf16x8 f;
            f[0] = (__bf16)a.x; f[1] = (__bf16)a.y; f[2] = (__bf16)a.z; f[3] = (__bf16)a.w;
            f[4] = (__bf16)b.x; f[5] = (__bf16)b.y; f[6] = (__bf16)b.z; f[7] = (__bf16)b.w;
            bfr[ni][kc] = f;
#pragma unroll
            for (int j = 0; j < 8; ++j) { float v = (float)f[j]; s += v * v; }
        }
        s += __shfl_xor(s, 16, 64);
        s += __shfl_xor(s, 32, 64);   // norm of col col0+ni*16+l16 (replicated)
        cn[ni] = s;
    }
    // epilogue needs norm of col col0+ni*16+quad*4+rg -> width-16 shuffle
    f32x4 ncv[4];
#pragma unroll
    for (int ni = 0; ni < 4; ++ni)
#pragma unroll
        for (int rg = 0; rg < 4; ++rg)
            ncv[ni][rg] = __shfl(cn[ni], quad * 4 + rg, 16);

    // all 32 MFMAs before the wait (swapped operands: acc[rg] = 4 consecutive cols)
    f32x4 acc[2][4];
#pragma unroll
    for (int mi = 0; mi < 2; ++mi)
#pragma unroll
        for (int ni = 0; ni < 4; ++ni) {
            f32x4 a = {0.f, 0.f, 0.f, 0.f};
#pragma unroll
            for (int kc = 0; kc < 4; ++kc)
                a = __builtin_amdgcn_mfma_f32_16x16x32_bf16(bfr[ni][kc], afr[mi][kc], a, 0, 0, 0);
            acc[mi][ni] = a;
        }
    __builtin_amdgcn_sched_barrier(0);   // don't sink loads/MFMA below the spin

    // ---------------- wait for all producer partials (BOUNDED) -------------
    if (wave == 0) {
        int tries = 0;
        for (;;) {
            unsigned long long f0 = __hip_atomic_load(&flags[lane], __ATOMIC_ACQUIRE,
                                                      __HIP_MEMORY_SCOPE_AGENT);
            unsigned long long f1 = __hip_atomic_load(&flags[lane + 64], __ATOMIC_ACQUIRE,
                                                      __HIP_MEMORY_SCOPE_AGENT);
            if (__all(f0 == FLAGVAL && f1 == FLAGVAL)) break;
            if (++tries > (1 << 20)) break;   // never legitimately reached:
                                              // turns any protocol bug into a
                                              // diagnosable wrong-result, not a hang
            __builtin_amdgcn_s_sleep(1);
        }
    }
    __syncthreads();
    __threadfence();   // acquire side: invalidate so s_part reads are fresh

    // ---------------- sigma: reduce k-major partials -----------------------
    const f32x4* sp = reinterpret_cast<const f32x4*>(
        s_part + (size_t)(t >> 1) * PB + (t & 1) * 64);
    f32x4 pa = {0.f, 0.f, 0.f, 0.f};
#pragma unroll
    for (int q = 0; q < 16; ++q) pa += sp[q];
    float sh = pa[0] + pa[1] + pa[2] + pa[3];
    float Sk = sh + __shfl_xor(sh, 1, 64);       // full column sum S_k
    float vv = (t & 1) ? 0.f : Sk * Sk;
    float nsv = (t < PB) ? nsum_part[t] : 0.f;
#pragma unroll
    for (int off = 32; off; off >>= 1) {
        vv  += __shfl_xor(vv, off, 64);
        nsv += __shfl_xor(nsv, off, 64);
    }
    if (lane == 0) { red[wave * 2] = vv; red[wave * 2 + 1] = nsv; }
    __syncthreads();
    const float V  = red[0] + red[2] + red[4] + red[6];
    const float NS = red[1] + red[3] + red[5] + red[7];
    const float invn = 1.f / (float)N;
    const float meand2 = 2.f * invn * (NS - V * invn);
    const float scale2 = -1.44269504088896f / (2.f * ALPHA * meand2); // log2e folded

    // ---------------- epilogue: d2 -> exp2 -> dwordx4 stores ---------------
#pragma unroll
    for (int mi = 0; mi < 2; ++mi) {
        float* orow = out + (size_t)(row0 + mi * 16 + l16) * N + col0 + quad * 4;
#pragma unroll
        for (int ni = 0; ni < 4; ++ni) {
            f32x4 rv;
#pragma unroll
            for (int rg = 0; rg < 4; ++rg) {
                float d2 = fmaxf(nr[mi] + ncv[ni][rg] - 2.f * acc[mi][ni][rg], 0.f);
                rv[rg] = __builtin_amdgcn_exp2f(scale2 * d2);
            }
            __builtin_nontemporal_store(rv, reinterpret_cast<f32x4*>(orow + ni * 16));
        }
    }
}

extern "C" void kernel_launch(void* const* d_in, const int* in_sizes, int n_in,
                              void* d_out, int out_size, void* d_ws, size_t ws_size,
                              hipStream_t stream) {
    const float* X = (const float*)d_in[0];
    float* out = (float*)d_out;
    char* ws = (char*)d_ws;

    float* s_part = (float*)(ws + WS_SP);
    float* nsum_p = (float*)(ws + WS_NS);
    unsigned long long* flags = (unsigned long long*)(ws + WS_FLAG);

    dim3 grid(N / 64, N / 128);   // (32,16) = 512 blocks
    gk_fused<<<grid, 256, 0, stream>>>(X, s_part, nsum_p, flags, out);
}

// Round 5
// 69.430 us; speedup vs baseline: 1.9153x; 1.9153x over previous
//
#include <hip/hip_runtime.h>
#include <stdint.h>

#define N 2048
#define F 128
#define ALPHA 1.0f
#define NPROD 32    // producer blocks, 64 rows each
#define RBID  32    // reducer block id

typedef __bf16 bf16x8 __attribute__((ext_vector_type(8)));
typedef float f32x4 __attribute__((ext_vector_type(4)));
typedef unsigned long long u64;

// ws layout (all cross-block data accessed ONLY via relaxed agent atomics):
//   [0, 16K)  : s_part[128][NPROD] - column-sum partials, K-MAJOR flat[k*32+b]
//   +16K      : nsum_part[NPROD]   - per-producer sum of row norms
//   +16K+128  : flags[NPROD] (u64) - per-producer magic pair {M, ~M}
//   +16K+384  : pub (u64)          - {scale2_bits, scale2_bits ^ MAGIC}
static constexpr size_t WS_SP   = 0;
static constexpr size_t WS_NS   = (size_t)F * NPROD * 4;     // 16384
static constexpr size_t WS_FLAG = WS_NS + (size_t)NPROD * 4; // 16512
static constexpr size_t WS_PUB  = WS_FLAG + (size_t)NPROD * 8;

// Single fused kernel, grid (32,16) = 512 blocks x 256 threads, all co-resident
// (launch_bounds(256,2): 2 blocks/CU x 256 CU = 512 slots -> no dispatch-order
// deadlock). NO agent-scope fences anywhere: round 4 showed each threadfence
// forces a dirty-L2 writeback of the freshly poisoned 256 MiB ws (~80 us total).
// Instead: relaxed agent atomics (write-through to the coherent point) +
// __syncthreads vmcnt-drain for producer-side ordering. All spins BOUNDED.
__global__ __launch_bounds__(256, 2) void gk_fused(
    const float* __restrict__ X,
    float* __restrict__ s_part,
    float* __restrict__ nsum_part,
    u64* __restrict__ flags,
    u64* __restrict__ pub,
    float* __restrict__ out)
{
    __shared__ float s_lds[F];
    __shared__ float nw_lds[4];
    __shared__ float red[8];
    __shared__ float sh_sc;

    const int t = threadIdx.x;
    const int bid = blockIdx.y * 32 + blockIdx.x;
    const int wave = t >> 6, lane = t & 63;
    const int quad = lane >> 4, l16 = lane & 15;

    // Data-derived magic (|1 so MAGIC != 0): no uniform 4-byte poison pattern
    // can fake either the flag pair (hi == ~lo) or the pub pair (hi == lo^MAGIC).
    const unsigned int MAGIC = (__float_as_uint(X[0]) ^ 0xB5297A4Du) | 1u;
    const u64 FLAGVAL = (u64)MAGIC | ((u64)(~MAGIC) << 32);

    // ---------------- producers: colsum + norm-sum partials ----------------
    if (bid < NPROD) {
        if (t < F) s_lds[t] = 0.f;
        __syncthreads();
        const int rl = t >> 4, kidx = t & 15, k0 = kidx * 8;
        float cs[8] = {0.f,0.f,0.f,0.f,0.f,0.f,0.f,0.f};
        float ns = 0.f;
#pragma unroll
        for (int p = 0; p < 4; ++p) {
            const int row = bid * 64 + p * 16 + rl;
            const float4* px = reinterpret_cast<const float4*>(X + (size_t)row * F + k0);
            float4 v0 = px[0], v1 = px[1];
            float xv[8] = {v0.x,v0.y,v0.z,v0.w,v1.x,v1.y,v1.z,v1.w};
#pragma unroll
            for (int j = 0; j < 8; ++j) {
                float fb = (float)(__bf16)xv[j];      // RNE to bf16 and back
                cs[j] += fb;
                ns += fb * fb;
            }
        }
        // sum of row norms over this block's 64 rows
        float nsr = ns;
#pragma unroll
        for (int off = 1; off < 64; off <<= 1) nsr += __shfl_xor(nsr, off, 64);
        if (lane == 0) nw_lds[wave] = nsr;
        // column sums: reduce within wave (bits 4,5 = row-groups), then LDS
#pragma unroll
        for (int j = 0; j < 8; ++j) {
            float cj = cs[j];
            cj += __shfl_xor(cj, 16, 64);
            cj += __shfl_xor(cj, 32, 64);
            if ((t & 48) == 0) atomicAdd(&s_lds[k0 + j], cj);
        }
        __syncthreads();
        // publish partials: relaxed agent atomics = write-through, no flushes
        if (t < F)
            __hip_atomic_store(&s_part[(size_t)t * NPROD + bid], s_lds[t],
                               __ATOMIC_RELAXED, __HIP_MEMORY_SCOPE_AGENT);
        if (t == 0)
            __hip_atomic_store(&nsum_part[bid],
                               nw_lds[0] + nw_lds[1] + nw_lds[2] + nw_lds[3],
                               __ATOMIC_RELAXED, __HIP_MEMORY_SCOPE_AGENT);
        __syncthreads();   // vmcnt(0) drain for ALL waves -> stores globally done
        if (t == 0)
            __hip_atomic_store(&flags[bid], FLAGVAL,
                               __ATOMIC_RELAXED, __HIP_MEMORY_SCOPE_AGENT);
    }

    // ---------------- reducer: flags -> sigma -> publish scale2 ------------
    if (bid == RBID) {
        if (wave == 0) {
            int tries = 0;
            for (;;) {
                u64 f = (lane < NPROD)
                    ? __hip_atomic_load(&flags[lane], __ATOMIC_RELAXED,
                                        __HIP_MEMORY_SCOPE_AGENT)
                    : FLAGVAL;
                if (__all(f == FLAGVAL)) break;
                if (++tries > 65536) break;   // protocol bug -> wrong result, not hang
                __builtin_amdgcn_s_sleep(1);
            }
        }
        __syncthreads();
        // coalesced atomic read of flat s_part[4096]; per (wave,i) chunk of 64:
        // lanes 0-31 hold all 32 partials of k = wave*32+2i, lanes 32-63 of k+1
        float vacc = 0.f;
#pragma unroll
        for (int i = 0; i < 16; ++i) {
            float v = __hip_atomic_load(&s_part[wave * 1024 + i * 64 + lane],
                                        __ATOMIC_RELAXED, __HIP_MEMORY_SCOPE_AGENT);
            v += __shfl_xor(v, 1, 64);
            v += __shfl_xor(v, 2, 64);
            v += __shfl_xor(v, 4, 64);
            v += __shfl_xor(v, 8, 64);
            v += __shfl_xor(v, 16, 64);       // S_k replicated in each 32-group
            if ((lane & 31) == 0) vacc += v * v;
        }
        float nsv = (wave == 0 && lane < NPROD)
            ? __hip_atomic_load(&nsum_part[lane], __ATOMIC_RELAXED,
                                __HIP_MEMORY_SCOPE_AGENT)
            : 0.f;
#pragma unroll
        for (int off = 32; off; off >>= 1) {
            vacc += __shfl_xor(vacc, off, 64);
            nsv  += __shfl_xor(nsv, off, 64);
        }
        if (lane == 0) { red[wave * 2] = vacc; red[wave * 2 + 1] = nsv; }
        __syncthreads();
        if (t == 0) {
            const float V  = red[0] + red[2] + red[4] + red[6];
            const float NS = red[1] + red[3] + red[5] + red[7];
            const float invn = 1.f / (float)N;
            const float meand2 = 2.f * invn * (NS - V * invn);
            const float s2 = -1.44269504088896f / (2.f * ALPHA * meand2);
            const unsigned int lo = __float_as_uint(s2);
            __hip_atomic_store(pub, (u64)lo | ((u64)(lo ^ MAGIC) << 32),
                               __ATOMIC_RELAXED, __HIP_MEMORY_SCOPE_AGENT);
            sh_sc = s2;
        }
    }

    // ---------------- block-local: fragments + norms + MFMA ----------------
    const int row0 = blockIdx.y * 128 + wave * 32;
    const int col0 = blockIdx.x * 64;

    bf16x8 afr[2][4];
    float nr[2];
#pragma unroll
    for (int mi = 0; mi < 2; ++mi) {
        const float* base = X + (size_t)(row0 + mi * 16 + l16) * F;
        float s = 0.f;
#pragma unroll
        for (int kc = 0; kc < 4; ++kc) {
            const float4* p = reinterpret_cast<const float4*>(base + (kc * 4 + quad) * 8);
            float4 a = p[0], b = p[1];
            bf16x8 f;
            f[0] = (__bf16)a.x; f[1] = (__bf16)a.y; f[2] = (__bf16)a.z; f[3] = (__bf16)a.w;
            f[4] = (__bf16)b.x; f[5] = (__bf16)b.y; f[6] = (__bf16)b.z; f[7] = (__bf16)b.w;
            afr[mi][kc] = f;
#pragma unroll
            for (int j = 0; j < 8; ++j) { float v = (float)f[j]; s += v * v; }
        }
        s += __shfl_xor(s, 16, 64);
        s += __shfl_xor(s, 32, 64);
        nr[mi] = s;
    }

    bf16x8 bfr[4][4];
    float cn[4];
#pragma unroll
    for (int ni = 0; ni < 4; ++ni) {
        const float* base = X + (size_t)(col0 + ni * 16 + l16) * F;
        float s = 0.f;
#pragma unroll
        for (int kc = 0; kc < 4; ++kc) {
            const float4* p = reinterpret_cast<const float4*>(base + (kc * 4 + quad) * 8);
            float4 a = p[0], b = p[1];
            bf16x8 f;
            f[0] = (__bf16)a.x; f[1] = (__bf16)a.y; f[2] = (__bf16)a.z; f[3] = (__bf16)a.w;
            f[4] = (__bf16)b.x; f[5] = (__bf16)b.y; f[6] = (__bf16)b.z; f[7] = (__bf16)b.w;
            bfr[ni][kc] = f;
#pragma unroll
            for (int j = 0; j < 8; ++j) { float v = (float)f[j]; s += v * v; }
        }
        s += __shfl_xor(s, 16, 64);
        s += __shfl_xor(s, 32, 64);
        cn[ni] = s;
    }
    f32x4 ncv[4];
#pragma unroll
    for (int ni = 0; ni < 4; ++ni)
#pragma unroll
        for (int rg = 0; rg < 4; ++rg)
            ncv[ni][rg] = __shfl(cn[ni], quad * 4 + rg, 16);

    // all 32 MFMAs before the scale wait (swapped operands: acc = 4 consec cols)
    f32x4 acc[2][4];
#pragma unroll
    for (int mi = 0; mi < 2; ++mi)
#pragma unroll
        for (int ni = 0; ni < 4; ++ni) {
            f32x4 a = {0.f, 0.f, 0.f, 0.f};
#pragma unroll
            for (int kc = 0; kc < 4; ++kc)
                a = __builtin_amdgcn_mfma_f32_16x16x32_bf16(bfr[ni][kc], afr[mi][kc], a, 0, 0, 0);
            acc[mi][ni] = a;
        }
    __builtin_amdgcn_sched_barrier(0);   // don't sink frag loads/MFMA below the poll

    // ---------------- acquire scale2 (one 8B poll per block) ---------------
    if (bid != RBID && t == 0) {
        u64 p;
        int tries = 0;
        for (;;) {
            p = __hip_atomic_load(pub, __ATOMIC_RELAXED, __HIP_MEMORY_SCOPE_AGENT);
            if ((unsigned int)(p >> 32) == ((unsigned int)p ^ MAGIC)) break;
            if (++tries > 65536) break;
            __builtin_amdgcn_s_sleep(2);
        }
        sh_sc = __uint_as_float((unsigned int)p);
    }
    __syncthreads();
    const float scale2 = sh_sc;           // -log2(e)/(2*alpha*meand2)

    // ---------------- epilogue: d2 -> exp2 -> dwordx4 stores ---------------
#pragma unroll
    for (int mi = 0; mi < 2; ++mi) {
        float* orow = out + (size_t)(row0 + mi * 16 + l16) * N + col0 + quad * 4;
#pragma unroll
        for (int ni = 0; ni < 4; ++ni) {
            f32x4 rv;
#pragma unroll
            for (int rg = 0; rg < 4; ++rg) {
                float d2 = fmaxf(nr[mi] + ncv[ni][rg] - 2.f * acc[mi][ni][rg], 0.f);
                rv[rg] = __builtin_amdgcn_exp2f(scale2 * d2);
            }
            __builtin_nontemporal_store(rv, reinterpret_cast<f32x4*>(orow + ni * 16));
        }
    }
}

extern "C" void kernel_launch(void* const* d_in, const int* in_sizes, int n_in,
                              void* d_out, int out_size, void* d_ws, size_t ws_size,
                              hipStream_t stream) {
    const float* X = (const float*)d_in[0];
    float* out = (float*)d_out;
    char* ws = (char*)d_ws;

    float* s_part = (float*)(ws + WS_SP);
    float* nsum_p = (float*)(ws + WS_NS);
    u64*   flags  = (u64*)(ws + WS_FLAG);
    u64*   pub    = (u64*)(ws + WS_PUB);

    dim3 grid(N / 64, N / 128);   // (32,16) = 512 blocks
    gk_fused<<<grid, 256, 0, stream>>>(X, s_part, nsum_p, flags, pub, out);
}

// Round 6
// 66.683 us; speedup vs baseline: 1.9942x; 1.0412x over previous
//
#include <hip/hip_runtime.h>
#include <stdint.h>

#define N 2048
#define F 128
#define ALPHA 1.0f
#define PB 32   // producer blocks, 64 rows each

typedef __bf16 bf16x8 __attribute__((ext_vector_type(8)));
typedef float f32x4 __attribute__((ext_vector_type(4)));

// ws layout:
//   [0, 512K)  : Xs         - bf16 X, fragment-major swizzled:
//                element (row,k) -> Xs[(row>>4)*2048 + (k>>3)*128 + (row&15)*8 + (k&7)]
//   then       : nrm[2048]       - row squared norms (of bf16-rounded X)
//   then       : s_part[128][PB] - column sums, K-MAJOR: s_part[k][b] (16 KB)
//   then       : nsum_part[PB]   - per-prep-block sum of row norms
static constexpr size_t WS_XS    = 0;
static constexpr size_t WS_N     = (size_t)N * F * 2;              // 524288
static constexpr size_t WS_SP    = WS_N + (size_t)N * 4;           // +8192
static constexpr size_t WS_NSUMP = WS_SP + (size_t)F * PB * 4;     // +16384

// ---------------- prep: fp32 -> bf16 (swizzled), row norms, column partials --
// 32 blocks x 256 threads, 4 row-passes each (loop structure validated in r5).
__global__ __launch_bounds__(256) void gk_prep(const float* __restrict__ X,
                                               ushort* __restrict__ Xs,
                                               float* __restrict__ nrm,
                                               float* __restrict__ s_part,
                                               float* __restrict__ nsum_part) {
    __shared__ float s_lds[F];
    __shared__ float nw_lds[4];
    const int t = threadIdx.x;
    if (t < F) s_lds[t] = 0.f;
    __syncthreads();

    const int rl = t >> 4, kidx = t & 15, k0 = kidx * 8;
    const int wave = t >> 6, lane = t & 63;

    float cs[8] = {0.f,0.f,0.f,0.f,0.f,0.f,0.f,0.f};
    float nsacc = 0.f;
#pragma unroll
    for (int p = 0; p < 4; ++p) {
        const int row = blockIdx.x * 64 + p * 16 + rl;
        const float4* px = reinterpret_cast<const float4*>(X + (size_t)row * F + k0);
        float4 v0 = px[0], v1 = px[1];
        float xv[8] = {v0.x, v0.y, v0.z, v0.w, v1.x, v1.y, v1.z, v1.w};
        uint32_t us[8];
        float ns = 0.f;
#pragma unroll
        for (int j = 0; j < 8; ++j) {
            uint32_t u = __float_as_uint(xv[j]);
            u = (u + 0x7FFFu + ((u >> 16) & 1u)) >> 16;   // RNE truncate to bf16
            us[j] = u;
            float fb = __uint_as_float(u << 16);
            cs[j] += fb;
            ns += fb * fb;
        }
        uint4 packed;
        packed.x = us[0] | (us[1] << 16);
        packed.y = us[2] | (us[3] << 16);
        packed.z = us[4] | (us[5] << 16);
        packed.w = us[6] | (us[7] << 16);
        // swizzled store: row>>4 = blockIdx.x*4+p, row&15 = rl
        *reinterpret_cast<uint4*>(Xs + (size_t)(blockIdx.x * 4 + p) * 2048
                                  + kidx * 128 + rl * 8) = packed;
        nsacc += ns;
        // row norm: butterfly over the 16 lanes sharing this row (low 4 bits)
        float nsr = ns;
#pragma unroll
        for (int off = 1; off < 16; off <<= 1) nsr += __shfl_xor(nsr, off, 64);
        if (kidx == 0) nrm[row] = nsr;
    }

    // block norm-sum: full-wave butterfly then LDS combine
    float nsw = nsacc;
#pragma unroll
    for (int off = 1; off < 64; off <<= 1) nsw += __shfl_xor(nsw, off, 64);
    if (lane == 0) nw_lds[wave] = nsw;

    // column sums: reduce 4 row-groups within wave, then 4-way LDS atomics
#pragma unroll
    for (int j = 0; j < 8; ++j) {
        float cj = cs[j];
        cj += __shfl_xor(cj, 16, 64);
        cj += __shfl_xor(cj, 32, 64);
        if ((lane & 48) == 0) atomicAdd(&s_lds[k0 + j], cj);
    }
    __syncthreads();

    // k-major partial store: s_part[k][blockIdx.x]
    if (t < F) s_part[(size_t)t * PB + blockIdx.x] = s_lds[t];
    if (t == 0) nsum_part[blockIdx.x] = nw_lds[0] + nw_lds[1] + nw_lds[2] + nw_lds[3];
}

// ---------------- main: C = exp(-(n_i + n_j - 2 X X^T) / (2 sigma^2)) -------
// block = 256 threads (4 waves); block tile 128 rows x 64 cols; wave tile 32x64.
// MFMA operands swapped: acc[rg] holds 4 consecutive output COLUMNS of one row
// -> dwordx4 nontemporal stores. One __syncthreads (sigma combine), no atomics.
__global__ __launch_bounds__(256) void gk_main(const __bf16* __restrict__ Xs,
                                               const float* __restrict__ nrm,
                                               const float* __restrict__ s_part,
                                               const float* __restrict__ nsum_part,
                                               float* __restrict__ out) {
    __shared__ float red[8];   // [wave]{v, nsum}
    const int t = threadIdx.x;
    const int wave = t >> 6, lane = t & 63;
    const int quad = lane >> 4, l16 = lane & 15;

    const int row0 = blockIdx.y * 128 + wave * 32;
    const int col0 = blockIdx.x * 64;

    // Fragment loads from swizzled layout: one contiguous 1 KB per wave-load.
    bf16x8 afr[2][4], bfr[4][4];
#pragma unroll
    for (int mi = 0; mi < 2; ++mi) {
        const size_t gbase = (size_t)((row0 + mi * 16) >> 4) * 2048;
#pragma unroll
        for (int kc = 0; kc < 4; ++kc)
            afr[mi][kc] = *reinterpret_cast<const bf16x8*>(
                Xs + gbase + (kc * 4 + quad) * 128 + l16 * 8);
    }
#pragma unroll
    for (int ni = 0; ni < 4; ++ni) {
        const size_t gbase = (size_t)((col0 + ni * 16) >> 4) * 2048;
#pragma unroll
        for (int kc = 0; kc < 4; ++kc)
            bfr[ni][kc] = *reinterpret_cast<const bf16x8*>(
                Xs + gbase + (kc * 4 + quad) * 128 + l16 * 8);
    }

    // Norms for the swapped layout: row i = row0+mi*16+l16 (per lane),
    // col j = col0+ni*16+quad*4+rg (4 consecutive per acc reg).
    float nr[2];
#pragma unroll
    for (int mi = 0; mi < 2; ++mi) nr[mi] = nrm[row0 + mi * 16 + l16];
    f32x4 ncv[4];
#pragma unroll
    for (int ni = 0; ni < 4; ++ni)
        ncv[ni] = *reinterpret_cast<const f32x4*>(nrm + col0 + ni * 16 + quad * 4);

    // Sigma from k-major partials (16 KB total, L2-hot): thread t sums half of
    // k-row (t>>1): 4 contiguous float4 loads; latency hides under frag loads.
    const f32x4* sp = reinterpret_cast<const f32x4*>(
        s_part + (size_t)(t >> 1) * PB + (t & 1) * 16);
    f32x4 pa = {0.f, 0.f, 0.f, 0.f};
#pragma unroll
    for (int q = 0; q < 4; ++q) pa += sp[q];
    float sh = pa[0] + pa[1] + pa[2] + pa[3];
    float Sk = sh + __shfl_xor(sh, 1, 64);       // full column sum S_k
    float vv = (t & 1) ? 0.f : Sk * Sk;
    float nsv = (t < PB) ? nsum_part[t] : 0.f;   // wave 0, lanes 0..31
#pragma unroll
    for (int off = 32; off; off >>= 1) {
        vv  += __shfl_xor(vv, off, 64);
        nsv += __shfl_xor(nsv, off, 64);
    }
    if (lane == 0) { red[wave * 2] = vv; red[wave * 2 + 1] = nsv; }
    __syncthreads();
    const float V  = red[0] + red[2] + red[4] + red[6];
    const float NS = red[1] + red[3] + red[5] + red[7];
    const float invn = 1.f / (float)N;
    const float meand2 = 2.f * invn * (NS - V * invn);
    // fold log2(e) into scale; epilogue uses raw v_exp_f32 (exp2)
    const float scale2 = -1.44269504088896f / (2.f * ALPHA * meand2);

#pragma unroll
    for (int mi = 0; mi < 2; ++mi) {
        float* orow = out + (size_t)(row0 + mi * 16 + l16) * N + col0 + quad * 4;
#pragma unroll
        for (int ni = 0; ni < 4; ++ni) {
            f32x4 acc = {0.f, 0.f, 0.f, 0.f};
#pragma unroll
            for (int kc = 0; kc < 4; ++kc)
                acc = __builtin_amdgcn_mfma_f32_16x16x32_bf16(bfr[ni][kc], afr[mi][kc], acc, 0, 0, 0);
            f32x4 rv;
#pragma unroll
            for (int rg = 0; rg < 4; ++rg) {
                float d2 = fmaxf(nr[mi] + ncv[ni][rg] - 2.f * acc[rg], 0.f);
                rv[rg] = __builtin_amdgcn_exp2f(scale2 * d2);
            }
            __builtin_nontemporal_store(rv, reinterpret_cast<f32x4*>(orow + ni * 16));
        }
    }
}

extern "C" void kernel_launch(void* const* d_in, const int* in_sizes, int n_in,
                              void* d_out, int out_size, void* d_ws, size_t ws_size,
                              hipStream_t stream) {
    const float* X = (const float*)d_in[0];
    float* out = (float*)d_out;
    char* ws = (char*)d_ws;

    ushort* Xs      = (ushort*)(ws + WS_XS);
    float*  nrm     = (float*)(ws + WS_N);
    float*  s_part  = (float*)(ws + WS_SP);
    float*  nsum_p  = (float*)(ws + WS_NSUMP);

    gk_prep<<<PB, 256, 0, stream>>>(X, Xs, nrm, s_part, nsum_p);

    dim3 grid(N / 64, N / 128);   // x: col tiles (64), y: row tiles (128)
    gk_main<<<grid, 256, 0, stream>>>((const __bf16*)Xs, nrm, s_part, nsum_p, out);
}